// Round 11
// baseline (110.088 us; speedup 1.0000x reference)
//
#include <hip/hip_runtime.h>
#include <hip/hip_bf16.h>
#include <math.h>

// Problem dims
#define D_MODEL   1024
#define D_INNER   2048
#define NHEADS    32
#define HEADDIM   64
#define D_STATE   64
#define CONV_DIM  2176            // D_INNER + 2*D_STATE
#define D_IN_PROJ 4256            // 2*D_INNER + 2*D_STATE + NHEADS
#define ZXLD      4352            // padded to 128
#define BATCH     2
#define SEQLEN    1024
#define BL        (BATCH * SEQLEN)
#define RMS_EPS   1.1920929e-07f

#define QCHUNK 64
#define NC     (SEQLEN / QCHUNK)

typedef __attribute__((ext_vector_type(8))) short short8;
typedef __attribute__((ext_vector_type(4))) float f32x4;
typedef __attribute__((ext_vector_type(8))) unsigned short ushort8v;
typedef __attribute__((ext_vector_type(4))) unsigned short ushort4v;

__device__ __forceinline__ unsigned short f2bf(float f) {
    unsigned u = __builtin_bit_cast(unsigned, f);
    unsigned r = u + 0x7FFFu + ((u >> 16) & 1u);   // RTNE
    return (unsigned short)(r >> 16);
}
__device__ __forceinline__ float bf2f(unsigned short u) {
    unsigned v = ((unsigned)u) << 16;
    return __builtin_bit_cast(float, v);
}
__device__ __forceinline__ void gload_lds16(const void* g, void* l) {
    __builtin_amdgcn_global_load_lds(
        (const __attribute__((address_space(1))) void*)g,
        (__attribute__((address_space(3))) void*)l, 16, 0, 0);
}

#define MFMA_BF16 __builtin_amdgcn_mfma_f32_16x16x32_bf16

// ---------------------------------------------------------------------------
// bf16 MFMA GEMM, NT (BK=64 single-buffer, LDS XOR swizzle, XCD block remap)
// ---------------------------------------------------------------------------
template<int BM, int BN, int WR, int WC, bool OBF16>
__global__ __launch_bounds__(256) void gemm_bf16_nt(
    const unsigned short* __restrict__ A, const unsigned short* __restrict__ B,
    void* __restrict__ Cv, int K, int ldc, int nbx)
{
    constexpr int RM = BM / WR;
    constexpr int RN = BN / WC;
    constexpr int MF = RM / 16;
    constexpr int NF = RN / 16;
    constexpr int GA = BM / 32;
    constexpr int GB = BN / 32;

    __shared__ unsigned short As[BM][64];
    __shared__ unsigned short Bs[BN][64];

    const int tid  = threadIdx.x;
    const int lane = tid & 63;
    const int w    = tid >> 6;
    const int wm   = w / WC;
    const int wn   = w % WC;

    const int nwg  = nbx * gridDim.y;
    const int cpx  = nwg >> 3;
    const int orig = blockIdx.y * nbx + blockIdx.x;
    const int swz  = (orig & 7) * cpx + (orig >> 3);
    const int bx   = swz % nbx;
    const int by   = swz / nbx;
    const int m0   = by * BM;
    const int n0   = bx * BN;

    const int srow  = lane >> 3;
    const int sslot = (lane & 7) ^ srow;

    const int fr  = lane & 15;
    const int hq  = lane >> 4;
    const int fr7 = fr & 7;

    f32x4 acc[MF][NF];
#pragma unroll
    for (int mi = 0; mi < MF; ++mi)
#pragma unroll
        for (int ni = 0; ni < NF; ++ni) acc[mi][ni] = (f32x4){0.f, 0.f, 0.f, 0.f};

    for (int k0 = 0; k0 < K; k0 += 64) {
        __syncthreads();
#pragma unroll
        for (int q = 0; q < GA; ++q) {
            const int g8 = (w * GA + q) * 8;
            gload_lds16(A + (size_t)(m0 + g8 + srow) * K + k0 + sslot * 8,
                        &As[g8][0]);
        }
#pragma unroll
        for (int q = 0; q < GB; ++q) {
            const int g8 = (w * GB + q) * 8;
            gload_lds16(B + (size_t)(n0 + g8 + srow) * K + k0 + sslot * 8,
                        &Bs[g8][0]);
        }
        __syncthreads();

#pragma unroll
        for (int ks = 0; ks < 2; ++ks) {
            const int slot = (ks * 4 + hq) ^ fr7;
            short8 av[MF], bv[NF];
#pragma unroll
            for (int mi = 0; mi < MF; ++mi)
                av[mi] = *(const short8*)&As[wm * RM + mi * 16 + fr][slot * 8];
#pragma unroll
            for (int ni = 0; ni < NF; ++ni)
                bv[ni] = *(const short8*)&Bs[wn * RN + ni * 16 + fr][slot * 8];
#pragma unroll
            for (int mi = 0; mi < MF; ++mi)
#pragma unroll
                for (int ni = 0; ni < NF; ++ni)
                    acc[mi][ni] = MFMA_BF16(av[mi], bv[ni], acc[mi][ni], 0, 0, 0);
        }
    }

    const int crow = (lane >> 4) * 4;
    const int ccol = lane & 15;
#pragma unroll
    for (int mi = 0; mi < MF; ++mi)
#pragma unroll
        for (int ni = 0; ni < NF; ++ni) {
            const int row0 = m0 + wm * RM + mi * 16 + crow;
            const int col  = n0 + wn * RN + ni * 16 + ccol;
#pragma unroll
            for (int r = 0; r < 4; ++r) {
                if constexpr (OBF16) {
                    ((unsigned short*)Cv)[(size_t)(row0 + r) * ldc + col] =
                        f2bf(acc[mi][ni][r]);
                } else {
                    ((float*)Cv)[(size_t)(row0 + r) * ldc + col] = acc[mi][ni][r];
                }
            }
        }
}

// ---------------------------------------------------------------------------
// merged fp32->bf16 casts
// ---------------------------------------------------------------------------
#define CAST_N1 (BL * D_MODEL / 4)
#define CAST_N2 (ZXLD * D_MODEL / 4)
#define CAST_N3 (D_MODEL * D_INNER / 4)

__global__ __launch_bounds__(256) void cast_all_kernel(
    const float* __restrict__ x, const float* __restrict__ W_in,
    const float* __restrict__ W_out,
    unsigned short* __restrict__ xb, unsigned short* __restrict__ winb,
    unsigned short* __restrict__ woutb)
{
    const int i = blockIdx.x * 256 + threadIdx.x;
    if (i < CAST_N1) {
        float4 v = *(const float4*)(x + (size_t)i * 4);
        ushort4 o = {f2bf(v.x), f2bf(v.y), f2bf(v.z), f2bf(v.w)};
        *(ushort4*)(xb + (size_t)i * 4) = o;
    } else if (i < CAST_N1 + CAST_N2) {
        const int j = i - CAST_N1;
        const int e0 = j * 4;
        const int row = e0 >> 10;
        ushort4 o = {0, 0, 0, 0};
        if (row < D_IN_PROJ) {
            float4 v = *(const float4*)(W_in + (size_t)e0);
            o.x = f2bf(v.x); o.y = f2bf(v.y); o.z = f2bf(v.z); o.w = f2bf(v.w);
        }
        *(ushort4*)(winb + (size_t)e0) = o;
    } else if (i < CAST_N1 + CAST_N2 + CAST_N3) {
        const int j = i - CAST_N1 - CAST_N2;
        float4 v = *(const float4*)(W_out + (size_t)j * 4);
        ushort4 o = {f2bf(v.x), f2bf(v.y), f2bf(v.z), f2bf(v.w)};
        *(ushort4*)(woutb + (size_t)j * 4) = o;
    }
}

// ---------------------------------------------------------------------------
// conv+silu for one 64-row x 16-channel slab (4-tap causal), from bf16 zxb
// ---------------------------------------------------------------------------
__device__ __forceinline__ void conv_rows16(
    const unsigned short* __restrict__ zxb, int grow0, int l0, int chbase,
    const float* __restrict__ conv_w, const float* __restrict__ conv_b,
    int r, int q, unsigned short o[16])
{
    float in[4][16];
#pragma unroll
    for (int k = 0; k < 4; ++k) {
        const int ll = l0 + r - 3 + k;
        if (ll >= 0) {
            const unsigned short* src =
                zxb + (size_t)(grow0 + r - 3 + k) * ZXLD + (D_INNER + chbase + q);
            ushort8v v0 = *(const ushort8v*)(src);
            ushort8v v1 = *(const ushort8v*)(src + 8);
#pragma unroll
            for (int j = 0; j < 8; ++j) { in[k][j] = bf2f(v0[j]); in[k][8 + j] = bf2f(v1[j]); }
        } else {
#pragma unroll
            for (int j = 0; j < 16; ++j) in[k][j] = 0.f;
        }
    }
#pragma unroll
    for (int j = 0; j < 16; ++j) {
        const int ch = chbase + q + j;
        const float4 wv = *(const float4*)(conv_w + ch * 4);
        float a = conv_b[ch];
        a = fmaf(in[0][j], wv.x, a);
        a = fmaf(in[1][j], wv.y, a);
        a = fmaf(in[2][j], wv.z, a);
        a = fmaf(in[3][j], wv.w, a);
        o[j] = f2bf(a / (1.f + __expf(-a)));
    }
}

// ---------------------------------------------------------------------------
// conv_scan: conv+silu fused with dt/cumsum + Phase-A state MFMA.
// grid (NC, 17, BATCH):
//   g < 16 : heads 2g,2g+1 (as R10)
//   g == 16: B/C natural tiles -> Bcc, Ccc  AND  G = C.B^T (fp32) -> Gcc.
//            G is head-independent (NGROUPS=1) — hoisted out of the 32
//            chunk_output head-blocks (32x dedup).
// ---------------------------------------------------------------------------
__global__ __launch_bounds__(256) void conv_scan_kernel(
    const unsigned short* __restrict__ zxb,
    const float* __restrict__ conv_w, const float* __restrict__ conv_b,
    const float* __restrict__ dt_bias, const float* __restrict__ A_log,
    unsigned short* __restrict__ xTb, unsigned short* __restrict__ Bcc,
    unsigned short* __restrict__ Ccc, float* __restrict__ Gcc,
    unsigned short* __restrict__ Sb,
    float* __restrict__ cumA, float* __restrict__ dtt)
{
    const int c = blockIdx.x;
    const int g = blockIdx.y;
    const int b = blockIdx.z;
    const int tid = threadIdx.x;
    const int lane = tid & 63;
    const int w = tid >> 6;

    const int l0 = c * QCHUNK;
    const int grow0 = b * SEQLEN + l0;
    const int r = tid >> 2;             // conv row
    const int q = (tid & 3) * 16;       // conv channel offset
    unsigned short o[16];

    if (g == 16) {   // B/C natural tiles + head-independent G = C.B^T
        __shared__ unsigned short sBn[64][72];
        __shared__ unsigned short sCn[64][72];
        const size_t ctile = ((size_t)b * NC + c) * 4096;

        conv_rows16(zxb, grow0, l0, 2048, conv_w, conv_b, r, q, o);
        {
            unsigned short* dst = Bcc + ctile + (size_t)r * 64 + q;
            ushort8v w0, w1;
#pragma unroll
            for (int j = 0; j < 8; ++j) { w0[j] = o[j]; w1[j] = o[8 + j]; }
            *(ushort8v*)dst = w0;
            *(ushort8v*)(dst + 8) = w1;
#pragma unroll
            for (int j = 0; j < 8; ++j) { sBn[r][q + j] = o[j]; sBn[r][q + 8 + j] = o[8 + j]; }
        }
        conv_rows16(zxb, grow0, l0, 2048 + 64, conv_w, conv_b, r, q, o);
        {
            unsigned short* dst = Ccc + ctile + (size_t)r * 64 + q;
            ushort8v w0, w1;
#pragma unroll
            for (int j = 0; j < 8; ++j) { w0[j] = o[j]; w1[j] = o[8 + j]; }
            *(ushort8v*)dst = w0;
            *(ushort8v*)(dst + 8) = w1;
#pragma unroll
            for (int j = 0; j < 8; ++j) { sCn[r][q + j] = o[j]; sCn[r][q + 8 + j] = o[8 + j]; }
        }
        __syncthreads();

        // G[t][s] = sum_n C[t,n]*B[s,n]  (NT, both natural)
        const int fr = lane & 15;
        const int ko = (lane >> 4) * 8;
        const int trow = w * 16 + (lane >> 4) * 4;
        short8 aC0 = *(const short8*)&sCn[w * 16 + fr][ko];
        short8 aC1 = *(const short8*)&sCn[w * 16 + fr][ko + 32];
        float* gout = Gcc + ctile;
#pragma unroll
        for (int j = 0; j < 4; ++j) {
            short8 b0 = *(const short8*)&sBn[j * 16 + fr][ko];
            short8 b1 = *(const short8*)&sBn[j * 16 + fr][ko + 32];
            f32x4 a = (f32x4){0.f, 0.f, 0.f, 0.f};
            a = MFMA_BF16(aC0, b0, a, 0, 0, 0);
            a = MFMA_BF16(aC1, b1, a, 0, 0, 0);
            const int s = j * 16 + fr;
#pragma unroll
            for (int rr = 0; rr < 4; ++rr)
                gout[(size_t)(trow + rr) * 64 + s] = a[rr];
        }
        return;
    }

    __shared__ unsigned short L[64][138];
    __shared__ unsigned short sBT[64][72];
    __shared__ unsigned short sXT[64][72];
    __shared__ float sw[2][64];

    // --- B-conv -> natural L; dt+cumsum by waves 0/1 ---
    conv_rows16(zxb, grow0, l0, 2048, conv_w, conv_b, r, q, o);
#pragma unroll
    for (int j = 0; j < 8; ++j) { L[r][q + j] = o[j]; L[r][q + 8 + j] = o[8 + j]; }

    if (w < 2) {
        const int h = g * 2 + w;
        const float A = -__expf(A_log[h]);
        const float vraw = bf2f(zxb[(size_t)(grow0 + lane) * ZXLD +
                                    (D_INNER + CONV_DIM) + h]) + dt_bias[h];
        const float dtv = (vraw > 20.f) ? vraw : log1pf(__expf(vraw));
        float cum = dtv * A;
#pragma unroll
        for (int off = 1; off < 64; off <<= 1) {
            const float t = __shfl_up(cum, off, 64);
            if (lane >= off) cum += t;
        }
        const float cum_end = __shfl(cum, 63, 64);
        sw[w][lane] = __expf(cum_end - cum) * dtv;
        cumA[(((size_t)b * NHEADS + h) * NC + c) * QCHUNK + lane] = cum;
        dtt[((size_t)b * NHEADS + h) * SEQLEN + l0 + lane] = dtv;
    }
    __syncthreads();

    const int cc = tid >> 2;
    const int tseg = (tid & 3) * 16;
#pragma unroll
    for (int j = 0; j < 16; ++j) sBT[cc][tseg + j] = L[tseg + j][cc];
    __syncthreads();

    const int fr = lane & 15;
    const int ko = (lane >> 4) * 8;
    const int nrow = w * 16 + (lane >> 4) * 4;

    for (int hh = 0; hh < 2; ++hh) {
        const int h = g * 2 + hh;
        conv_rows16(zxb, grow0, l0, h * 64, conv_w, conv_b, r, q, o);
#pragma unroll
        for (int j = 0; j < 8; ++j) { L[r][q + j] = o[j]; L[r][q + 8 + j] = o[8 + j]; }
        __syncthreads();

        unsigned short tv[16];
#pragma unroll
        for (int j = 0; j < 16; ++j) tv[j] = L[tseg + j][cc];
        {
            unsigned short* dstT =
                xTb + (((size_t)b * NHEADS + h) * NC + c) * 4096 + (size_t)cc * 64 + tseg;
            ushort8v w0, w1;
#pragma unroll
            for (int j = 0; j < 8; ++j) { w0[j] = tv[j]; w1[j] = tv[8 + j]; }
            *(ushort8v*)dstT = w0;
            *(ushort8v*)(dstT + 8) = w1;
        }
#pragma unroll
        for (int j = 0; j < 16; ++j)
            sXT[cc][tseg + j] = f2bf(bf2f(tv[j]) * sw[hh][tseg + j]);
        __syncthreads();

        short8 a0 = *(const short8*)&sBT[w * 16 + fr][ko];
        short8 a1 = *(const short8*)&sBT[w * 16 + fr][ko + 32];
        unsigned short* sout = Sb + (((size_t)b * NHEADS + h) * NC + c) * 4096;
#pragma unroll
        for (int j = 0; j < 4; ++j) {
            short8 b0 = *(const short8*)&sXT[j * 16 + fr][ko];
            short8 b1 = *(const short8*)&sXT[j * 16 + fr][ko + 32];
            f32x4 a = (f32x4){0.f, 0.f, 0.f, 0.f};
            a = MFMA_BF16(a0, b0, a, 0, 0, 0);
            a = MFMA_BF16(a1, b1, a, 0, 0, 0);
            const int p = j * 16 + fr;
#pragma unroll
            for (int rr = 0; rr < 4; ++rr)
                sout[(size_t)(nrow + rr) * HEADDIM + p] = f2bf(a[rr]);
        }
        __syncthreads();
    }
}

// ---------------------------------------------------------------------------
// Phase B: inter-chunk recurrence on bf16 S (elementwise, 256 blocks)
// ---------------------------------------------------------------------------
__global__ __launch_bounds__(256) void state_pass_kernel(
    unsigned short* __restrict__ S, const float* __restrict__ cumA)
{
    const int gid = blockIdx.x * 256 + threadIdx.x;
    const int bh = gid >> 10;
    const int e0 = (gid & 1023) * 4;

    float run[4] = {0.f, 0.f, 0.f, 0.f};
    unsigned short* base = S + (size_t)bh * NC * (D_STATE * HEADDIM) + e0;

    ushort4v pre = *(const ushort4v*)base;
    float gpre = __expf(cumA[((size_t)bh * NC) * QCHUNK + (QCHUNK - 1)]);

    for (int c = 0; c < NC; ++c) {
        const ushort4v cur = pre;
        const float g = gpre;
        if (c + 1 < NC) {
            pre = *(const ushort4v*)(base + (size_t)(c + 1) * (D_STATE * HEADDIM));
            gpre = __expf(cumA[((size_t)bh * NC + c + 1) * QCHUNK + (QCHUNK - 1)]);
        }
        ushort4v o;
#pragma unroll
        for (int j = 0; j < 4; ++j) o[j] = f2bf(run[j]);
        *(ushort4v*)(base + (size_t)c * (D_STATE * HEADDIM)) = o;
#pragma unroll
        for (int j = 0; j < 4; ++j) run[j] = fmaf(g, run[j], bf2f(cur[j]));
    }
}

// ---------------------------------------------------------------------------
// Phase C (MFMA): M = mask(G_precomputed)*exp(dcum)*dt; Y = M.X + exp(cum)*C.SP + D*x
// ---------------------------------------------------------------------------
__global__ __launch_bounds__(256) void chunk_output_kernel(
    const unsigned short* __restrict__ xTb, const float* __restrict__ Gcc,
    const unsigned short* __restrict__ Ccc, const float* __restrict__ dtt,
    const unsigned short* __restrict__ SP, const float* __restrict__ cumA,
    const float* __restrict__ D_param, unsigned short* __restrict__ y)
{
    const int bid = blockIdx.x;
    const int c = bid & (NC - 1);
    const int h = (bid >> 4) & (NHEADS - 1);
    const int b = bid >> 9;
    const int tid = threadIdx.x;
    const int lane = tid & 63;
    const int w = tid >> 6;

    __shared__ unsigned short sC[64][72];
    __shared__ unsigned short sXT[64][72];
    __shared__ unsigned short sSPT[64][72];
    __shared__ unsigned short sM[64][72];
    __shared__ float scum[64], sdt[64];

    const size_t ctile = ((size_t)b * NC + c) * 4096;
    {
        const int r = tid >> 2, q = (tid & 3) * 16;
        const unsigned short* cs = Ccc + ctile + (size_t)r * 64 + q;
        *(ushort8v*)&sC[r][q]     = *(const ushort8v*)(cs);
        *(ushort8v*)&sC[r][q + 8] = *(const ushort8v*)(cs + 8);
        const unsigned short* xs =
            xTb + (((size_t)b * NHEADS + h) * NC + c) * 4096 + (size_t)r * 64 + q;
        *(ushort8v*)&sXT[r][q]     = *(const ushort8v*)(xs);
        *(ushort8v*)&sXT[r][q + 8] = *(const ushort8v*)(xs + 8);
        const unsigned short* ss = SP + (size_t)bid * (D_STATE * HEADDIM) + (size_t)r * 64 + q;
        ushort8v v0 = *(const ushort8v*)(ss);
        ushort8v v1 = *(const ushort8v*)(ss + 8);
#pragma unroll
        for (int j = 0; j < 8; ++j) { sSPT[q + j][r] = v0[j]; sSPT[q + 8 + j][r] = v1[j]; }
    }
    if (tid < QCHUNK) {
        scum[tid] = cumA[(size_t)bid * QCHUNK + tid];
        sdt[tid] = dtt[((size_t)b * NHEADS + h) * SEQLEN + c * QCHUNK + tid];
    }

    const int fr = lane & 15;
    const int ko = (lane >> 4) * 8;
    const int trow = w * 16 + (lane >> 4) * 4;

    // M from precomputed G (head-independent, fp32 in L2)
    const float* gb = Gcc + ctile;
    float gv[4][4];
#pragma unroll
    for (int j = 0; j < 4; ++j) {
        const int s = j * 16 + fr;
#pragma unroll
        for (int r = 0; r < 4; ++r)
            gv[j][r] = gb[(size_t)(trow + r) * 64 + s];
    }
    __syncthreads();   // scum/sdt + staging visible

    float ct[4];
#pragma unroll
    for (int r = 0; r < 4; ++r) ct[r] = scum[trow + r];
#pragma unroll
    for (int j = 0; j < 4; ++j) {
        const int s = j * 16 + fr;
        const float cs = scum[s], ds = sdt[s];
#pragma unroll
        for (int r = 0; r < 4; ++r) {
            const int t = trow + r;
            const float m = (s <= t) ? gv[j][r] * __expf(ct[r] - cs) * ds : 0.f;
            sM[t][s] = f2bf(m);
        }
    }
    __syncthreads();

    short8 aC0 = *(const short8*)&sC[w * 16 + fr][ko];
    short8 aC1 = *(const short8*)&sC[w * 16 + fr][ko + 32];
    short8 aM0 = *(const short8*)&sM[w * 16 + fr][ko];
    short8 aM1 = *(const short8*)&sM[w * 16 + fr][ko + 32];
    f32x4 y1[4], y2[4];
#pragma unroll
    for (int j = 0; j < 4; ++j) {
        short8 bx0 = *(const short8*)&sXT[j * 16 + fr][ko];
        short8 bx1 = *(const short8*)&sXT[j * 16 + fr][ko + 32];
        f32x4 a = (f32x4){0.f, 0.f, 0.f, 0.f};
        a = MFMA_BF16(aM0, bx0, a, 0, 0, 0);
        a = MFMA_BF16(aM1, bx1, a, 0, 0, 0);
        y1[j] = a;
        short8 bs0 = *(const short8*)&sSPT[j * 16 + fr][ko];
        short8 bs1 = *(const short8*)&sSPT[j * 16 + fr][ko + 32];
        f32x4 a2 = (f32x4){0.f, 0.f, 0.f, 0.f};
        a2 = MFMA_BF16(aC0, bs0, a2, 0, 0, 0);
        a2 = MFMA_BF16(aC1, bs1, a2, 0, 0, 0);
        y2[j] = a2;
    }

    const float Dp = D_param[h];
    float et[4];
#pragma unroll
    for (int r = 0; r < 4; ++r) et[r] = __expf(ct[r]);
    unsigned short* ybase = y + (((size_t)b * SEQLEN + c * QCHUNK) * D_INNER) + h * HEADDIM;
#pragma unroll
    for (int j = 0; j < 4; ++j) {
        const int p = j * 16 + fr;
#pragma unroll
        for (int r = 0; r < 4; ++r) {
            const int t = trow + r;
            const float xv = bf2f(sXT[p][t]);
            ybase[(size_t)t * D_INNER + p] = f2bf(y1[j][r] + et[r] * y2[j][r] + Dp * xv);
        }
    }
}

// ---------------------------------------------------------------------------
// RMSNorm * norm_w * silu(z) -> bf16
// ---------------------------------------------------------------------------
__global__ __launch_bounds__(256) void rms_gate_kernel(
    const unsigned short* __restrict__ y, const unsigned short* __restrict__ zxb,
    const float* __restrict__ norm_w, unsigned short* __restrict__ out)
{
    const int m = blockIdx.x;
    const int tid = threadIdx.x;
    const unsigned short* yr = y + (size_t)m * D_INNER;
    const unsigned short* zr = zxb + (size_t)m * ZXLD;

    ushort8v yv8 = *(const ushort8v*)(yr + tid * 8);
    float yv[8];
#pragma unroll
    for (int j = 0; j < 8; ++j) yv[j] = bf2f(yv8[j]);
    float ss = 0.f;
#pragma unroll
    for (int j = 0; j < 8; ++j) ss += yv[j] * yv[j];
#pragma unroll
    for (int off = 32; off > 0; off >>= 1) ss += __shfl_xor(ss, off, 64);
    __shared__ float sred[4];
    if ((tid & 63) == 0) sred[tid >> 6] = ss;
    __syncthreads();
    const float tot = sred[0] + sred[1] + sred[2] + sred[3];
    const float inv = rsqrtf(tot * (1.f / D_INNER) + RMS_EPS);

    ushort8v zv8 = *(const ushort8v*)(zr + tid * 8);
    const float* nw = norm_w + tid * 8;
    ushort8v o;
#pragma unroll
    for (int j = 0; j < 8; ++j) {
        const float zz = bf2f(zv8[j]);
        const float sig = 1.f / (1.f + __expf(-zz));
        o[j] = f2bf(yv[j] * inv * nw[j] * (zz * sig));
    }
    *(ushort8v*)(out + (size_t)m * D_INNER + tid * 8) = o;
}

// ---------------------------------------------------------------------------
extern "C" void kernel_launch(void* const* d_in, const int* in_sizes, int n_in,
                              void* d_out, int out_size, void* d_ws, size_t ws_size,
                              hipStream_t stream)
{
    const float* x       = (const float*)d_in[0];
    const float* W_in    = (const float*)d_in[1];
    const float* conv_w  = (const float*)d_in[2];
    const float* conv_b  = (const float*)d_in[3];
    const float* dt_bias = (const float*)d_in[4];
    const float* A_log   = (const float*)d_in[5];
    const float* D_param = (const float*)d_in[6];
    const float* norm_w  = (const float*)d_in[7];
    const float* W_out   = (const float*)d_in[8];
    float* out = (float*)d_out;

    char* p = (char*)d_ws;
    unsigned short* zxb   = (unsigned short*)p;  p += (size_t)BL * ZXLD * 2;
    float*          dtt   = (float*)p;           p += (size_t)BATCH * NHEADS * SEQLEN * 4;
    float*          cumA  = (float*)p;           p += (size_t)BATCH * NHEADS * SEQLEN * 4;
    unsigned short* Sb    = (unsigned short*)p;  p += (size_t)BATCH * NHEADS * NC * 4096 * 2;
    unsigned short* xTb   = (unsigned short*)p;  p += (size_t)BATCH * NHEADS * NC * 4096 * 2;
    unsigned short* Bcc   = (unsigned short*)p;  p += (size_t)BATCH * NC * 4096 * 2;
    unsigned short* Ccc   = (unsigned short*)p;  p += (size_t)BATCH * NC * 4096 * 2;
    float*          Gcc   = (float*)p;           p += (size_t)BATCH * NC * 4096 * 4;
    unsigned short* ybb   = (unsigned short*)p;  p += (size_t)BL * D_INNER * 2;
    unsigned short* xb    = (unsigned short*)p;  p += (size_t)BL * D_MODEL * 2;
    unsigned short* winb  = (unsigned short*)p;  p += (size_t)ZXLD * D_MODEL * 2;
    unsigned short* woutb = (unsigned short*)p;  p += (size_t)D_MODEL * D_INNER * 2;
    unsigned short* ygb   = (unsigned short*)p;

    // 0) merged casts
    cast_all_kernel<<<(CAST_N1 + CAST_N2 + CAST_N3 + 255) / 256, 256, 0, stream>>>(
        x, W_in, W_out, xb, winb, woutb);

    // 1) in_proj (bf16 MFMA -> bf16 zx)
    gemm_bf16_nt<128, 128, 2, 2, true><<<dim3(ZXLD / 128, BL / 128), 256, 0, stream>>>(
        xb, winb, zxb, D_MODEL, ZXLD, ZXLD / 128);

    // 2) conv+silu + dt + chunk-state + G (fused)
    conv_scan_kernel<<<dim3(NC, 17, BATCH), 256, 0, stream>>>(
        zxb, conv_w, conv_b, dt_bias, A_log, xTb, Bcc, Ccc, Gcc, Sb, cumA, dtt);
    // 3) inter-chunk recurrence
    state_pass_kernel<<<256, 256, 0, stream>>>(Sb, cumA);
    // 4) chunk output (uses precomputed G)
    chunk_output_kernel<<<BATCH * NHEADS * NC, 256, 0, stream>>>(
        xTb, Gcc, Ccc, dtt, Sb, cumA, D_param, ybb);
    // 5) RMSNorm + gate -> bf16
    rms_gate_kernel<<<BL, 256, 0, stream>>>(ybb, zxb, norm_w, ygb);

    // 6) out_proj (bf16 MFMA -> fp32 out)
    gemm_bf16_nt<64, 64, 2, 2, false><<<dim3(D_MODEL / 64, BL / 64), 256, 0, stream>>>(
        ygb, woutb, out, D_INNER, D_MODEL, D_MODEL / 64);
}

// Round 12
// 106.265 us; speedup vs baseline: 1.0360x; 1.0360x over previous
//
#include <hip/hip_runtime.h>
#include <hip/hip_bf16.h>
#include <math.h>

// Problem dims
#define D_MODEL   1024
#define D_INNER   2048
#define NHEADS    32
#define HEADDIM   64
#define D_STATE   64
#define CONV_DIM  2176            // D_INNER + 2*D_STATE
#define D_IN_PROJ 4256            // 2*D_INNER + 2*D_STATE + NHEADS
#define ZXLD      4352            // padded to 128
#define BATCH     2
#define SEQLEN    1024
#define BL        (BATCH * SEQLEN)
#define RMS_EPS   1.1920929e-07f

#define QCHUNK 64
#define NC     (SEQLEN / QCHUNK)

typedef __attribute__((ext_vector_type(8))) short short8;
typedef __attribute__((ext_vector_type(4))) float f32x4;
typedef __attribute__((ext_vector_type(8))) unsigned short ushort8v;
typedef __attribute__((ext_vector_type(4))) unsigned short ushort4v;

__device__ __forceinline__ unsigned short f2bf(float f) {
    unsigned u = __builtin_bit_cast(unsigned, f);
    unsigned r = u + 0x7FFFu + ((u >> 16) & 1u);   // RTNE
    return (unsigned short)(r >> 16);
}
__device__ __forceinline__ float bf2f(unsigned short u) {
    unsigned v = ((unsigned)u) << 16;
    return __builtin_bit_cast(float, v);
}
__device__ __forceinline__ void gload_lds16(const void* g, void* l) {
    __builtin_amdgcn_global_load_lds(
        (const __attribute__((address_space(1))) void*)g,
        (__attribute__((address_space(3))) void*)l, 16, 0, 0);
}

#define MFMA_BF16 __builtin_amdgcn_mfma_f32_16x16x32_bf16

// ---------------------------------------------------------------------------
// bf16 MFMA GEMM, NT (BK=64 single-buffer, LDS XOR swizzle, XCD block remap;
// nwg % 8 == 0 at both call sites).
// ---------------------------------------------------------------------------
template<int BM, int BN, int WR, int WC, bool OBF16>
__global__ __launch_bounds__(256) void gemm_bf16_nt(
    const unsigned short* __restrict__ A, const unsigned short* __restrict__ B,
    void* __restrict__ Cv, int K, int ldc, int nbx)
{
    constexpr int RM = BM / WR;
    constexpr int RN = BN / WC;
    constexpr int MF = RM / 16;
    constexpr int NF = RN / 16;
    constexpr int GA = BM / 32;
    constexpr int GB = BN / 32;

    __shared__ unsigned short As[BM][64];
    __shared__ unsigned short Bs[BN][64];

    const int tid  = threadIdx.x;
    const int lane = tid & 63;
    const int w    = tid >> 6;
    const int wm   = w / WC;
    const int wn   = w % WC;

    const int nwg  = nbx * gridDim.y;
    const int cpx  = nwg >> 3;
    const int orig = blockIdx.y * nbx + blockIdx.x;
    const int swz  = (orig & 7) * cpx + (orig >> 3);
    const int bx   = swz % nbx;
    const int by   = swz / nbx;
    const int m0   = by * BM;
    const int n0   = bx * BN;

    const int srow  = lane >> 3;
    const int sslot = (lane & 7) ^ srow;

    const int fr  = lane & 15;
    const int hq  = lane >> 4;
    const int fr7 = fr & 7;

    f32x4 acc[MF][NF];
#pragma unroll
    for (int mi = 0; mi < MF; ++mi)
#pragma unroll
        for (int ni = 0; ni < NF; ++ni) acc[mi][ni] = (f32x4){0.f, 0.f, 0.f, 0.f};

    for (int k0 = 0; k0 < K; k0 += 64) {
        __syncthreads();
#pragma unroll
        for (int q = 0; q < GA; ++q) {
            const int g8 = (w * GA + q) * 8;
            gload_lds16(A + (size_t)(m0 + g8 + srow) * K + k0 + sslot * 8,
                        &As[g8][0]);
        }
#pragma unroll
        for (int q = 0; q < GB; ++q) {
            const int g8 = (w * GB + q) * 8;
            gload_lds16(B + (size_t)(n0 + g8 + srow) * K + k0 + sslot * 8,
                        &Bs[g8][0]);
        }
        __syncthreads();

#pragma unroll
        for (int ks = 0; ks < 2; ++ks) {
            const int slot = (ks * 4 + hq) ^ fr7;
            short8 av[MF], bv[NF];
#pragma unroll
            for (int mi = 0; mi < MF; ++mi)
                av[mi] = *(const short8*)&As[wm * RM + mi * 16 + fr][slot * 8];
#pragma unroll
            for (int ni = 0; ni < NF; ++ni)
                bv[ni] = *(const short8*)&Bs[wn * RN + ni * 16 + fr][slot * 8];
#pragma unroll
            for (int mi = 0; mi < MF; ++mi)
#pragma unroll
                for (int ni = 0; ni < NF; ++ni)
                    acc[mi][ni] = MFMA_BF16(av[mi], bv[ni], acc[mi][ni], 0, 0, 0);
        }
    }

    const int crow = (lane >> 4) * 4;
    const int ccol = lane & 15;
#pragma unroll
    for (int mi = 0; mi < MF; ++mi)
#pragma unroll
        for (int ni = 0; ni < NF; ++ni) {
            const int row0 = m0 + wm * RM + mi * 16 + crow;
            const int col  = n0 + wn * RN + ni * 16 + ccol;
#pragma unroll
            for (int r = 0; r < 4; ++r) {
                if constexpr (OBF16) {
                    ((unsigned short*)Cv)[(size_t)(row0 + r) * ldc + col] =
                        f2bf(acc[mi][ni][r]);
                } else {
                    ((float*)Cv)[(size_t)(row0 + r) * ldc + col] = acc[mi][ni][r];
                }
            }
        }
}

// ---------------------------------------------------------------------------
// merged fp32->bf16 casts: x -> xb, W_in -> winb (row-padded), W_out -> woutb
// ---------------------------------------------------------------------------
#define CAST_N1 (BL * D_MODEL / 4)
#define CAST_N2 (ZXLD * D_MODEL / 4)
#define CAST_N3 (D_MODEL * D_INNER / 4)

__global__ __launch_bounds__(256) void cast_all_kernel(
    const float* __restrict__ x, const float* __restrict__ W_in,
    const float* __restrict__ W_out,
    unsigned short* __restrict__ xb, unsigned short* __restrict__ winb,
    unsigned short* __restrict__ woutb)
{
    const int i = blockIdx.x * 256 + threadIdx.x;
    if (i < CAST_N1) {
        float4 v = *(const float4*)(x + (size_t)i * 4);
        ushort4 o = {f2bf(v.x), f2bf(v.y), f2bf(v.z), f2bf(v.w)};
        *(ushort4*)(xb + (size_t)i * 4) = o;
    } else if (i < CAST_N1 + CAST_N2) {
        const int j = i - CAST_N1;
        const int e0 = j * 4;
        const int row = e0 >> 10;                   // D_MODEL = 1024
        ushort4 o = {0, 0, 0, 0};
        if (row < D_IN_PROJ) {
            float4 v = *(const float4*)(W_in + (size_t)e0);
            o.x = f2bf(v.x); o.y = f2bf(v.y); o.z = f2bf(v.z); o.w = f2bf(v.w);
        }
        *(ushort4*)(winb + (size_t)e0) = o;
    } else if (i < CAST_N1 + CAST_N2 + CAST_N3) {
        const int j = i - CAST_N1 - CAST_N2;
        float4 v = *(const float4*)(W_out + (size_t)j * 4);
        ushort4 o = {f2bf(v.x), f2bf(v.y), f2bf(v.z), f2bf(v.w)};
        *(ushort4*)(woutb + (size_t)j * 4) = o;
    }
}

// ---------------------------------------------------------------------------
// conv_pre: single-pass conv(4-tap causal)+silu over the conv strip of zxb,
// emitting chunk-tile layouts; g==17 slice computes dt=softplus (transposed).
// grid (NC, 18, BATCH).
// ---------------------------------------------------------------------------
__global__ __launch_bounds__(256) void conv_pre_kernel(
    const unsigned short* __restrict__ zxb,
    const float* __restrict__ conv_w, const float* __restrict__ conv_b,
    const float* __restrict__ dt_bias,
    unsigned short* __restrict__ xTb, unsigned short* __restrict__ Bcc,
    unsigned short* __restrict__ BTc, unsigned short* __restrict__ Ccc,
    float* __restrict__ dtt)
{
    const int c = blockIdx.x;
    const int g = blockIdx.y;
    const int b = blockIdx.z;
    const int tid = threadIdx.x;

    const int l0 = c * QCHUNK;
    const int grow0 = b * SEQLEN + l0;

    if (g == 17) {
        const int hd = tid & 31;
        const int t0 = (tid >> 5) * 8;
        const float bias = dt_bias[hd];
#pragma unroll
        for (int j = 0; j < 8; ++j) {
            const int row = t0 + j;
            const float v = bf2f(zxb[(size_t)(grow0 + row) * ZXLD +
                                     (D_INNER + CONV_DIM) + hd]) + bias;
            const float sp = (v > 20.f) ? v : log1pf(__expf(v));
            dtt[((size_t)b * NHEADS + hd) * SEQLEN + l0 + row] = sp;
        }
        return;
    }

    __shared__ unsigned short L[64][138];
    const int r = tid >> 2;
    const int q = (tid & 3) * 16;

    for (int hh = 0; hh < 2; ++hh) {
        const int chbase = g * 128 + hh * 64;
        float in[4][16];
#pragma unroll
        for (int k = 0; k < 4; ++k) {
            const int ll = l0 + r - 3 + k;
            if (ll >= 0) {
                const unsigned short* src =
                    zxb + (size_t)(grow0 + r - 3 + k) * ZXLD + (D_INNER + chbase + q);
                ushort8v v0 = *(const ushort8v*)(src);
                ushort8v v1 = *(const ushort8v*)(src + 8);
#pragma unroll
                for (int j = 0; j < 8; ++j) { in[k][j] = bf2f(v0[j]); in[k][8 + j] = bf2f(v1[j]); }
            } else {
#pragma unroll
                for (int j = 0; j < 16; ++j) in[k][j] = 0.f;
            }
        }
        unsigned short o[16];
#pragma unroll
        for (int j = 0; j < 16; ++j) {
            const int ch = chbase + q + j;
            const float4 wv = *(const float4*)(conv_w + ch * 4);
            float a = conv_b[ch];
            a = fmaf(in[0][j], wv.x, a);
            a = fmaf(in[1][j], wv.y, a);
            a = fmaf(in[2][j], wv.z, a);
            a = fmaf(in[3][j], wv.w, a);
            o[j] = f2bf(a / (1.f + __expf(-a)));
        }

        const bool isB = (g == 16) && (hh == 0);
        const bool isC = (g == 16) && (hh == 1);
        const size_t ctile = ((size_t)b * NC + c) * 4096;

        if (isB || isC) {
            unsigned short* dst = (isB ? Bcc : Ccc) + ctile + (size_t)r * 64 + q;
            ushort8v w0, w1;
#pragma unroll
            for (int j = 0; j < 8; ++j) { w0[j] = o[j]; w1[j] = o[8 + j]; }
            *(ushort8v*)dst = w0;
            *(ushort8v*)(dst + 8) = w1;
        }
        if (!isC) {
#pragma unroll
            for (int j = 0; j < 8; ++j) { L[r][q + j] = o[j]; L[r][q + 8 + j] = o[8 + j]; }
            __syncthreads();
            const int cc = tid >> 2;
            const int tseg = (tid & 3) * 16;
            unsigned short tv[16];
#pragma unroll
            for (int j = 0; j < 16; ++j) tv[j] = L[tseg + j][cc];
            unsigned short* dstT;
            if (isB) dstT = BTc + ctile + (size_t)cc * 64 + tseg;
            else {
                const int hgt = g * 2 + hh;
                dstT = xTb + (((size_t)b * NHEADS + hgt) * NC + c) * 4096 + (size_t)cc * 64 + tseg;
            }
            ushort8v w0, w1;
#pragma unroll
            for (int j = 0; j < 8; ++j) { w0[j] = tv[j]; w1[j] = tv[8 + j]; }
            *(ushort8v*)dstT = w0;
            *(ushort8v*)(dstT + 8) = w1;
        }
        __syncthreads();
    }
}

// ---------------------------------------------------------------------------
// Phase A (MFMA): S[n,p] = sum_t B[t,n] * (w_t*X[t,p]); identity staging.
// ---------------------------------------------------------------------------
__global__ __launch_bounds__(256) void chunk_state_kernel(
    const unsigned short* __restrict__ xTb, const unsigned short* __restrict__ BTc,
    const float* __restrict__ dtt, const float* __restrict__ A_log,
    unsigned short* __restrict__ Sintra, float* __restrict__ cumA)
{
    const int bid = blockIdx.x;
    const int c = bid & (NC - 1);
    const int h = (bid >> 4) & (NHEADS - 1);
    const int b = bid >> 9;
    const int tid = threadIdx.x;
    const int lane = tid & 63;
    const int w = tid >> 6;

    __shared__ unsigned short sXT[64][72];
    __shared__ unsigned short sBT[64][72];
    __shared__ float sw[64];

    if (tid < QCHUNK) {
        const float A = -__expf(A_log[h]);
        const float dtv = dtt[((size_t)b * NHEADS + h) * SEQLEN + c * QCHUNK + tid];
        float cum = dtv * A;
#pragma unroll
        for (int off = 1; off < 64; off <<= 1) {
            const float o = __shfl_up(cum, off, 64);
            if (tid >= off) cum += o;
        }
        const float cum_end = __shfl(cum, 63, 64);
        sw[tid] = __expf(cum_end - cum) * dtv;
        cumA[(size_t)bid * QCHUNK + tid] = cum;
    }
    __syncthreads();

    {
        const int r = tid >> 2, q = (tid & 3) * 16;
        const unsigned short* xs =
            xTb + (((size_t)b * NHEADS + h) * NC + c) * 4096 + (size_t)r * 64 + q;
        ushort8v v0 = *(const ushort8v*)(xs);
        ushort8v v1 = *(const ushort8v*)(xs + 8);
        ushort8v s0, s1;
#pragma unroll
        for (int j = 0; j < 8; ++j) {
            s0[j] = f2bf(bf2f(v0[j]) * sw[q + j]);
            s1[j] = f2bf(bf2f(v1[j]) * sw[q + 8 + j]);
        }
        *(ushort8v*)&sXT[r][q] = s0;
        *(ushort8v*)&sXT[r][q + 8] = s1;

        const unsigned short* bs =
            BTc + ((size_t)b * NC + c) * 4096 + (size_t)r * 64 + q;
        *(ushort8v*)&sBT[r][q]     = *(const ushort8v*)(bs);
        *(ushort8v*)&sBT[r][q + 8] = *(const ushort8v*)(bs + 8);
    }
    __syncthreads();

    const int fr = lane & 15;
    const int ko = (lane >> 4) * 8;
    short8 a0 = *(const short8*)&sBT[w * 16 + fr][ko];
    short8 a1 = *(const short8*)&sBT[w * 16 + fr][ko + 32];

    unsigned short* sout = Sintra + (size_t)bid * (D_STATE * HEADDIM);
    const int nrow = w * 16 + (lane >> 4) * 4;
#pragma unroll
    for (int j = 0; j < 4; ++j) {
        short8 b0 = *(const short8*)&sXT[j * 16 + fr][ko];
        short8 b1 = *(const short8*)&sXT[j * 16 + fr][ko + 32];
        f32x4 a = (f32x4){0.f, 0.f, 0.f, 0.f};
        a = MFMA_BF16(a0, b0, a, 0, 0, 0);
        a = MFMA_BF16(a1, b1, a, 0, 0, 0);
        const int p = j * 16 + fr;
#pragma unroll
        for (int r = 0; r < 4; ++r)
            sout[(size_t)(nrow + r) * HEADDIM + p] = f2bf(a[r]);
    }
}

// ---------------------------------------------------------------------------
// Phase B: inter-chunk recurrence on bf16 S (elementwise, 256 blocks)
// ---------------------------------------------------------------------------
__global__ __launch_bounds__(256) void state_pass_kernel(
    unsigned short* __restrict__ S, const float* __restrict__ cumA)
{
    const int gid = blockIdx.x * 256 + threadIdx.x;
    const int bh = gid >> 10;
    const int e0 = (gid & 1023) * 4;

    float run[4] = {0.f, 0.f, 0.f, 0.f};
    unsigned short* base = S + (size_t)bh * NC * (D_STATE * HEADDIM) + e0;

    ushort4v pre = *(const ushort4v*)base;
    float gpre = __expf(cumA[((size_t)bh * NC) * QCHUNK + (QCHUNK - 1)]);

    for (int c = 0; c < NC; ++c) {
        const ushort4v cur = pre;
        const float g = gpre;
        if (c + 1 < NC) {
            pre = *(const ushort4v*)(base + (size_t)(c + 1) * (D_STATE * HEADDIM));
            gpre = __expf(cumA[((size_t)bh * NC + c + 1) * QCHUNK + (QCHUNK - 1)]);
        }
        ushort4v o;
#pragma unroll
        for (int j = 0; j < 4; ++j) o[j] = f2bf(run[j]);
        *(ushort4v*)(base + (size_t)c * (D_STATE * HEADDIM)) = o;
#pragma unroll
        for (int j = 0; j < 4; ++j) run[j] = fmaf(g, run[j], bf2f(cur[j]));
    }
}

// ---------------------------------------------------------------------------
// Phase C (MFMA): G = C.B^T; M = mask(G)*exp(dcum)*dt; Y = M.X + exp(cum)*C.SP + D*x
// ---------------------------------------------------------------------------
__global__ __launch_bounds__(256) void chunk_output_kernel(
    const unsigned short* __restrict__ xTb, const unsigned short* __restrict__ Bcc,
    const unsigned short* __restrict__ Ccc, const float* __restrict__ dtt,
    const unsigned short* __restrict__ SP, const float* __restrict__ cumA,
    const float* __restrict__ D_param, unsigned short* __restrict__ y)
{
    const int bid = blockIdx.x;
    const int c = bid & (NC - 1);
    const int h = (bid >> 4) & (NHEADS - 1);
    const int b = bid >> 9;
    const int tid = threadIdx.x;
    const int lane = tid & 63;
    const int w = tid >> 6;

    __shared__ unsigned short sC[64][72];
    __shared__ unsigned short sB[64][72];
    __shared__ unsigned short sXT[64][72];
    __shared__ unsigned short sSPT[64][72];
    __shared__ unsigned short sM[64][72];
    __shared__ float scum[64], sdt[64];

    const size_t ctile = ((size_t)b * NC + c) * 4096;
    {
        const int r = tid >> 2, q = (tid & 3) * 16;
        const unsigned short* cs = Ccc + ctile + (size_t)r * 64 + q;
        *(ushort8v*)&sC[r][q]     = *(const ushort8v*)(cs);
        *(ushort8v*)&sC[r][q + 8] = *(const ushort8v*)(cs + 8);
        const unsigned short* bs = Bcc + ctile + (size_t)r * 64 + q;
        *(ushort8v*)&sB[r][q]     = *(const ushort8v*)(bs);
        *(ushort8v*)&sB[r][q + 8] = *(const ushort8v*)(bs + 8);
        const unsigned short* xs =
            xTb + (((size_t)b * NHEADS + h) * NC + c) * 4096 + (size_t)r * 64 + q;
        *(ushort8v*)&sXT[r][q]     = *(const ushort8v*)(xs);
        *(ushort8v*)&sXT[r][q + 8] = *(const ushort8v*)(xs + 8);
        const unsigned short* ss = SP + (size_t)bid * (D_STATE * HEADDIM) + (size_t)r * 64 + q;
        ushort8v v0 = *(const ushort8v*)(ss);
        ushort8v v1 = *(const ushort8v*)(ss + 8);
#pragma unroll
        for (int j = 0; j < 8; ++j) { sSPT[q + j][r] = v0[j]; sSPT[q + 8 + j][r] = v1[j]; }
    }
    if (tid < QCHUNK) {
        scum[tid] = cumA[(size_t)bid * QCHUNK + tid];
        sdt[tid] = dtt[((size_t)b * NHEADS + h) * SEQLEN + c * QCHUNK + tid];
    }
    __syncthreads();

    const int fr = lane & 15;
    const int ko = (lane >> 4) * 8;
    const int trow = w * 16 + (lane >> 4) * 4;

    short8 aC0 = *(const short8*)&sC[w * 16 + fr][ko];
    short8 aC1 = *(const short8*)&sC[w * 16 + fr][ko + 32];

    f32x4 g[4];
#pragma unroll
    for (int j = 0; j < 4; ++j) {
        short8 b0 = *(const short8*)&sB[j * 16 + fr][ko];
        short8 b1 = *(const short8*)&sB[j * 16 + fr][ko + 32];
        f32x4 a = (f32x4){0.f, 0.f, 0.f, 0.f};
        a = MFMA_BF16(aC0, b0, a, 0, 0, 0);
        a = MFMA_BF16(aC1, b1, a, 0, 0, 0);
        g[j] = a;
    }

    float ct[4];
#pragma unroll
    for (int r = 0; r < 4; ++r) ct[r] = scum[trow + r];
#pragma unroll
    for (int j = 0; j < 4; ++j) {
        const int s = j * 16 + fr;
        const float cs = scum[s], ds = sdt[s];
#pragma unroll
        for (int r = 0; r < 4; ++r) {
            const int t = trow + r;
            const float m = (s <= t) ? g[j][r] * __expf(ct[r] - cs) * ds : 0.f;
            sM[t][s] = f2bf(m);
        }
    }
    __syncthreads();

    short8 aM0 = *(const short8*)&sM[w * 16 + fr][ko];
    short8 aM1 = *(const short8*)&sM[w * 16 + fr][ko + 32];
    f32x4 y1[4], y2[4];
#pragma unroll
    for (int j = 0; j < 4; ++j) {
        short8 bx0 = *(const short8*)&sXT[j * 16 + fr][ko];
        short8 bx1 = *(const short8*)&sXT[j * 16 + fr][ko + 32];
        f32x4 a = (f32x4){0.f, 0.f, 0.f, 0.f};
        a = MFMA_BF16(aM0, bx0, a, 0, 0, 0);
        a = MFMA_BF16(aM1, bx1, a, 0, 0, 0);
        y1[j] = a;
        short8 bs0 = *(const short8*)&sSPT[j * 16 + fr][ko];
        short8 bs1 = *(const short8*)&sSPT[j * 16 + fr][ko + 32];
        f32x4 a2 = (f32x4){0.f, 0.f, 0.f, 0.f};
        a2 = MFMA_BF16(aC0, bs0, a2, 0, 0, 0);
        a2 = MFMA_BF16(aC1, bs1, a2, 0, 0, 0);
        y2[j] = a2;
    }

    const float Dp = D_param[h];
    float et[4];
#pragma unroll
    for (int r = 0; r < 4; ++r) et[r] = __expf(ct[r]);
    unsigned short* ybase = y + (((size_t)b * SEQLEN + c * QCHUNK) * D_INNER) + h * HEADDIM;
#pragma unroll
    for (int j = 0; j < 4; ++j) {
        const int p = j * 16 + fr;
#pragma unroll
        for (int r = 0; r < 4; ++r) {
            const int t = trow + r;
            const float xv = bf2f(sXT[p][t]);
            ybase[(size_t)t * D_INNER + p] = f2bf(y1[j][r] + et[r] * y2[j][r] + Dp * xv);
        }
    }
}

// ---------------------------------------------------------------------------
// RMSNorm * norm_w * silu(z) -> bf16; y and z read as bf16
// ---------------------------------------------------------------------------
__global__ __launch_bounds__(256) void rms_gate_kernel(
    const unsigned short* __restrict__ y, const unsigned short* __restrict__ zxb,
    const float* __restrict__ norm_w, unsigned short* __restrict__ out)
{
    const int m = blockIdx.x;
    const int tid = threadIdx.x;
    const unsigned short* yr = y + (size_t)m * D_INNER;
    const unsigned short* zr = zxb + (size_t)m * ZXLD;

    ushort8v yv8 = *(const ushort8v*)(yr + tid * 8);
    float yv[8];
#pragma unroll
    for (int j = 0; j < 8; ++j) yv[j] = bf2f(yv8[j]);
    float ss = 0.f;
#pragma unroll
    for (int j = 0; j < 8; ++j) ss += yv[j] * yv[j];
#pragma unroll
    for (int off = 32; off > 0; off >>= 1) ss += __shfl_xor(ss, off, 64);
    __shared__ float sred[4];
    if ((tid & 63) == 0) sred[tid >> 6] = ss;
    __syncthreads();
    const float tot = sred[0] + sred[1] + sred[2] + sred[3];
    const float inv = rsqrtf(tot * (1.f / D_INNER) + RMS_EPS);

    ushort8v zv8 = *(const ushort8v*)(zr + tid * 8);
    const float* nw = norm_w + tid * 8;
    ushort8v o;
#pragma unroll
    for (int j = 0; j < 8; ++j) {
        const float zz = bf2f(zv8[j]);
        const float sig = 1.f / (1.f + __expf(-zz));
        o[j] = f2bf(yv[j] * inv * nw[j] * (zz * sig));
    }
    *(ushort8v*)(out + (size_t)m * D_INNER + tid * 8) = o;
}

// ---------------------------------------------------------------------------
extern "C" void kernel_launch(void* const* d_in, const int* in_sizes, int n_in,
                              void* d_out, int out_size, void* d_ws, size_t ws_size,
                              hipStream_t stream)
{
    const float* x       = (const float*)d_in[0];
    const float* W_in    = (const float*)d_in[1];
    const float* conv_w  = (const float*)d_in[2];
    const float* conv_b  = (const float*)d_in[3];
    const float* dt_bias = (const float*)d_in[4];
    const float* A_log   = (const float*)d_in[5];
    const float* D_param = (const float*)d_in[6];
    const float* norm_w  = (const float*)d_in[7];
    const float* W_out   = (const float*)d_in[8];
    float* out = (float*)d_out;

    char* p = (char*)d_ws;
    unsigned short* zxb   = (unsigned short*)p;  p += (size_t)BL * ZXLD * 2;
    float*          dtt   = (float*)p;           p += (size_t)BATCH * NHEADS * SEQLEN * 4;
    float*          cumA  = (float*)p;           p += (size_t)BATCH * NHEADS * SEQLEN * 4;
    unsigned short* Sb    = (unsigned short*)p;  p += (size_t)BATCH * NHEADS * NC * 4096 * 2;
    unsigned short* xTb   = (unsigned short*)p;  p += (size_t)BATCH * NHEADS * NC * 4096 * 2;
    unsigned short* Bcc   = (unsigned short*)p;  p += (size_t)BATCH * NC * 4096 * 2;
    unsigned short* BTc   = (unsigned short*)p;  p += (size_t)BATCH * NC * 4096 * 2;
    unsigned short* Ccc   = (unsigned short*)p;  p += (size_t)BATCH * NC * 4096 * 2;
    unsigned short* ybb   = (unsigned short*)p;  p += (size_t)BL * D_INNER * 2;
    unsigned short* xb    = (unsigned short*)p;  p += (size_t)BL * D_MODEL * 2;
    unsigned short* winb  = (unsigned short*)p;  p += (size_t)ZXLD * D_MODEL * 2;
    unsigned short* woutb = (unsigned short*)p;  p += (size_t)D_MODEL * D_INNER * 2;
    unsigned short* ygb   = (unsigned short*)p;

    // 0) merged casts
    cast_all_kernel<<<(CAST_N1 + CAST_N2 + CAST_N3 + 255) / 256, 256, 0, stream>>>(
        x, W_in, W_out, xb, winb, woutb);

    // 1) in_proj (bf16 MFMA -> bf16 zx), 128x128, BK=64 single-buf + XCD swz
    gemm_bf16_nt<128, 128, 2, 2, true><<<dim3(ZXLD / 128, BL / 128), 256, 0, stream>>>(
        xb, winb, zxb, D_MODEL, ZXLD, ZXLD / 128);

    // 2) conv+silu (+dt softplus slice) -> chunk-tile layouts
    conv_pre_kernel<<<dim3(NC, 18, BATCH), 256, 0, stream>>>(
        zxb, conv_w, conv_b, dt_bias, xTb, Bcc, BTc, Ccc, dtt);
    // 3) chunked SSM scan
    chunk_state_kernel<<<BATCH * NHEADS * NC, 256, 0, stream>>>(
        xTb, BTc, dtt, A_log, Sb, cumA);
    state_pass_kernel<<<256, 256, 0, stream>>>(Sb, cumA);
    chunk_output_kernel<<<BATCH * NHEADS * NC, 256, 0, stream>>>(
        xTb, Bcc, Ccc, dtt, Sb, cumA, D_param, ybb);
    // 4) RMSNorm + gate -> bf16
    rms_gate_kernel<<<BL, 256, 0, stream>>>(ybb, zxb, norm_w, ygb);

    // 5) out_proj (bf16 MFMA -> fp32 out), 64x64, BK=64 single-buf + XCD swz
    gemm_bf16_nt<64, 64, 2, 2, false><<<dim3(D_MODEL / 64, BL / 64), 256, 0, stream>>>(
        ygb, woutb, out, D_INNER, D_MODEL, D_MODEL / 64);
}